// Round 1
// baseline (144.978 us; speedup 1.0000x reference)
//
#include <hip/hip_runtime.h>
#include <math.h>

#define H 512
#define PPAD 256          // 245 real (l,c) pairs, padded with zeros
#define KAPPA (1.0f/61.0f)

// ---------------------------------------------------------------------------
// Kernel 1: build V[h][p] = W1[l][h] * W2[h][c],  p = l*35 + c  (0..244), pad->256
// Layout: Vt[(h*64 + lane)*4 + j] holds V[h][p = j*64 + lane]  (float4 per lane)
// ---------------------------------------------------------------------------
__global__ void build_v(const float* __restrict__ W1, const float* __restrict__ W2,
                        float* __restrict__ Vt) {
    int t = blockIdx.x * blockDim.x + threadIdx.x;   // 0 .. 512*64-1
    if (t >= H * 64) return;
    int h = t >> 6, lane = t & 63;
    float4 out;
    float* o = reinterpret_cast<float*>(&out);
#pragma unroll
    for (int j = 0; j < 4; ++j) {
        int p = j * 64 + lane;
        float v = 0.f;
        if (p < 245) {
            int l = p / 35, c = p % 35;
            v = W1[l * H + h] * W2[h * 35 + c];
        }
        o[j] = v;
    }
    reinterpret_cast<float4*>(Vt)[t] = out;
}

// ---------------------------------------------------------------------------
// Kernel 2: main. 256 threads = 4 waves. Block handles 64 samples, each wave 16
// (2 groups of 8). Per group: compute g=1-tanh^2 into LDS, then contract
// against V (lane owns p = j*64+lane, j=0..3), square-reduce, per-wave partial.
// ---------------------------------------------------------------------------
__global__ __launch_bounds__(256, 2)
void torsion_main(const float* __restrict__ x, const float* __restrict__ W1,
                  const float* __restrict__ b1, const float* __restrict__ Vt,
                  float* __restrict__ partials, int nwaves) {
    __shared__ float xs[64][8];          // 64 samples x 7 (padded to 8)
    __shared__ float gw[4][8][H];        // per-wave g buffer: 8 samples x 512

    const int tid  = threadIdx.x;
    const int wave = tid >> 6;
    const int lane = tid & 63;
    const int blk  = blockIdx.x;

    // stage x tile (64 samples x 7)
    for (int i = tid; i < 64 * 7; i += 256) {
        int s = i / 7, l = i % 7;
        xs[s][l] = x[(size_t)(blk * 64 + s) * 7 + l];
    }
    __syncthreads();

    float wloss = 0.f, wnorm = 0.f;

    for (int grp = 0; grp < 2; ++grp) {
        const int sb = wave * 16 + grp * 8;   // local sample base for this wave

        // ---- phase 1: g = 1 - tanh(x@W1 + b1)^2 into LDS --------------------
#pragma unroll
        for (int k = 0; k < 8; ++k) {
            const int h = (k << 6) + lane;
            float w1v[7];
#pragma unroll
            for (int l = 0; l < 7; ++l) w1v[l] = W1[l * H + h];
            const float bb = b1[h];
#pragma unroll
            for (int s = 0; s < 8; ++s) {
                float pre = bb;
#pragma unroll
                for (int l = 0; l < 7; ++l) pre += xs[sb + s][l] * w1v[l];
                float th = tanhf(pre);
                gw[wave][s][h] = 1.f - th * th;
            }
        }
        // same-wave LDS ops are in-order; no block barrier needed (wave-private region)

        // ---- phase 2: J[s][p] = sum_h g[s][h] * V[h][p] ---------------------
        float acc[8][4];
#pragma unroll
        for (int s = 0; s < 8; ++s)
#pragma unroll
            for (int j = 0; j < 4; ++j) acc[s][j] = 0.f;

        const float4* vrow = reinterpret_cast<const float4*>(Vt) + lane;
        for (int h = 0; h < H; ++h) {
            float4 v = vrow[(size_t)h * 64];
            float gv[8];
#pragma unroll
            for (int s = 0; s < 8; ++s) gv[s] = gw[wave][s][h];   // broadcast reads
#pragma unroll
            for (int s = 0; s < 8; ++s) {
                acc[s][0] += gv[s] * v.x;
                acc[s][1] += gv[s] * v.y;
                acc[s][2] += gv[s] * v.z;
                acc[s][3] += gv[s] * v.w;
            }
        }

        // ---- reduce: q = 6 * ||J||_F^2 per sample ---------------------------
#pragma unroll
        for (int s = 0; s < 8; ++s) {
            float r = acc[s][0]*acc[s][0] + acc[s][1]*acc[s][1]
                    + acc[s][2]*acc[s][2] + acc[s][3]*acc[s][3];
#pragma unroll
            for (int off = 32; off; off >>= 1) r += __shfl_xor(r, off);
            float q = 6.f * r;
            float n = sqrtf(q + 1e-10f);
            float d = n - KAPPA;
            wloss += d * d;
            wnorm += n;
        }
    }

    if (lane == 0) {
        int widx = blk * 4 + wave;
        partials[widx]          = wloss;
        partials[nwaves + widx] = wnorm;
    }
}

// ---------------------------------------------------------------------------
// Kernel 3: finalize — deterministic reduction of per-wave partials.
// ---------------------------------------------------------------------------
__global__ void finalize_k(const float* __restrict__ partials, float* __restrict__ out,
                           int nwaves, float invB) {
    __shared__ float sl[256], sn[256];
    int tid = threadIdx.x;
    float l = 0.f, n = 0.f;
    for (int i = tid; i < nwaves; i += 256) {
        l += partials[i];
        n += partials[nwaves + i];
    }
    sl[tid] = l; sn[tid] = n;
    __syncthreads();
    for (int st = 128; st > 0; st >>= 1) {
        if (tid < st) { sl[tid] += sl[tid + st]; sn[tid] += sn[tid + st]; }
        __syncthreads();
    }
    if (tid == 0) {
        out[0] = sl[0] * invB;   // loss
        out[1] = sn[0] * invB;   // mean torsion norm
    }
}

// ---------------------------------------------------------------------------
extern "C" void kernel_launch(void* const* d_in, const int* in_sizes, int n_in,
                              void* d_out, int out_size, void* d_ws, size_t ws_size,
                              hipStream_t stream) {
    const float* x  = (const float*)d_in[0];
    const float* W1 = (const float*)d_in[1];
    const float* b1 = (const float*)d_in[2];
    const float* W2 = (const float*)d_in[3];
    // b2 (d_in[4]) is unused: the Jacobian kills the bias.

    const int B    = in_sizes[0] / 7;       // 32768
    const int nblk = B / 64;                // 512
    const int nwaves = nblk * 4;            // 2048

    float* Vt       = (float*)d_ws;                 // H * PPAD floats = 512 KB
    float* partials = Vt + (size_t)H * PPAD;        // 2 * nwaves floats
    float* out      = (float*)d_out;

    build_v<<<(H * 64 + 255) / 256, 256, 0, stream>>>(W1, W2, Vt);
    torsion_main<<<nblk, 256, 0, stream>>>(x, W1, b1, Vt, partials, nwaves);
    finalize_k<<<1, 256, 0, stream>>>(partials, out, nwaves, 1.0f / (float)B);
}

// Round 2
// 52.871 us; speedup vs baseline: 2.7421x; 2.7421x over previous
//
#include <hip/hip_runtime.h>
#include <math.h>

typedef __attribute__((ext_vector_type(8)))  short bf16x8;
typedef __attribute__((ext_vector_type(16))) float f32x16;
typedef __attribute__((ext_vector_type(4)))  float f32x4v;

#define KAPPA (1.0f/61.0f)
#define NBLK 256           // 32768 rows / 128 rows-per-block

__device__ __forceinline__ unsigned short f2bf(float f) {
    unsigned int x = __float_as_uint(f);
    x += 0x7fffu + ((x >> 16) & 1u);               // RNE
    return (unsigned short)(x >> 16);
}
__device__ __forceinline__ float bf2f(unsigned short u) {
    return __uint_as_float(((unsigned int)u) << 16);
}
__device__ __forceinline__ float fast_rcp(float v) {
#if __has_builtin(__builtin_amdgcn_rcpf)
    return __builtin_amdgcn_rcpf(v);
#else
    return 1.0f / v;
#endif
}

// ---------------------------------------------------------------------------
// Kernel 1: V[h][p] = W1[l][h]*W2[h][c] (p = l*35+c, padded to 256), stored as
// split-bf16 (hi/lo) in 32x32x16-MFMA B-fragment layout:
//   frag f = (kkg*8 + ntg)*64 + lane holds B[k = kkg*16+(lane>>5)*8+i][p = ntg*32+(lane&31)]
// ---------------------------------------------------------------------------
__global__ void build_v(const float* __restrict__ W1, const float* __restrict__ W2,
                        bf16x8* __restrict__ Vh, bf16x8* __restrict__ Vl) {
    int f = blockIdx.x * blockDim.x + threadIdx.x;   // 0..16383
    if (f >= 32 * 8 * 64) return;
    int lane = f & 63;
    int ntg  = (f >> 6) & 7;
    int kkg  = f >> 9;
    int p     = ntg * 32 + (lane & 31);
    int hbase = kkg * 16 + (lane >> 5) * 8;
    bool valid = (p < 245);
    int l7 = p / 35, c = p - l7 * 35;
    bf16x8 vh, vl;
#pragma unroll
    for (int i = 0; i < 8; ++i) {
        int h = hbase + i;
        float v = valid ? (W1[l7 * 512 + h] * W2[h * 35 + c]) : 0.0f;
        unsigned short hu = f2bf(v);
        float lo = v - bf2f(hu);
        vh[i] = (short)hu;
        vl[i] = (short)f2bf(lo);
    }
    Vh[f] = vh;
    Vl[f] = vl;
}

// ---------------------------------------------------------------------------
// Kernel 2: main. 512 threads = 8 waves = 2 row-groups x 4 p-groups.
// Block tile: 128 rows x 256 p. Wave tile: 64 rows x 64 p (2 rt x 2 nt of 32x32).
// Per 64-k chunk: phase A computes g = 1-tanh^2 split-bf16 into LDS in
// A-fragment layout; phase B runs 3-term split-bf16 MFMAs, V streamed from L2.
// ---------------------------------------------------------------------------
__global__ __launch_bounds__(512, 2)
void torsion_main(const float* __restrict__ x, const float* __restrict__ W1,
                  const float* __restrict__ b1,
                  const bf16x8* __restrict__ Vh, const bf16x8* __restrict__ Vl,
                  float* __restrict__ partials) {
    __shared__ float W1s[7 * 512];
    __shared__ float b1s[512];
    __shared__ __align__(16) short Gh[4 * 4 * 64 * 8];  // [kk][rg][lane][8]
    __shared__ __align__(16) short Gl[4 * 4 * 64 * 8];
    __shared__ float red[4][128];
    __shared__ float red2[2][128];

    const int tid  = threadIdx.x;
    const int blk  = blockIdx.x;
    const int lane = tid & 63;
    const int w    = tid >> 6;
    const int wrg  = w >> 2;      // row-group 0..1 (64 rows each)
    const int wpg  = w & 3;       // p-group 0..3 (64 p each)

    // stage W1 (7x512) + b1
    for (int i = tid; i < 7 * 512; i += 512) W1s[i] = W1[i];
    if (tid < 512) b1s[tid] = b1[tid];

    // phase-A work identity: slot covers (rg, lane'), kksel splits kk parity
    const int slot  = tid & 255;
    const int arg   = slot >> 6;                 // 0..3 (32-row group)
    const int alane = slot & 63;
    const int arow  = arg * 32 + (alane & 31);   // local row 0..127
    const int akoff = (alane >> 5) * 8;          // 0 or 8 within a 16-k step
    const int kksel = tid >> 8;                  // 0..1

    float xr[7];
    {
        const float* xp = x + ((size_t)blk * 128 + arow) * 7;
#pragma unroll
        for (int l = 0; l < 7; ++l) xr[l] = xp[l];
    }

    f32x16 acc[2][2];
#pragma unroll
    for (int rt = 0; rt < 2; ++rt)
#pragma unroll
        for (int nt = 0; nt < 2; ++nt)
#pragma unroll
            for (int e = 0; e < 16; ++e) acc[rt][nt][e] = 0.0f;

    __syncthreads();   // W1s/b1s ready

    for (int chunk = 0; chunk < 8; ++chunk) {
        // ---- phase A: g for k in [chunk*64, chunk*64+64), split bf16 -> LDS ----
#pragma unroll
        for (int j = 0; j < 2; ++j) {
            const int kk    = kksel + 2 * j;               // 0..3
            const int kbase = chunk * 64 + kk * 16 + akoff;
            f32x4v wv[7][2], bv[2];
#pragma unroll
            for (int l = 0; l < 7; ++l) {
                wv[l][0] = *reinterpret_cast<const f32x4v*>(&W1s[l * 512 + kbase]);
                wv[l][1] = *reinterpret_cast<const f32x4v*>(&W1s[l * 512 + kbase + 4]);
            }
            bv[0] = *reinterpret_cast<const f32x4v*>(&b1s[kbase]);
            bv[1] = *reinterpret_cast<const f32x4v*>(&b1s[kbase + 4]);
            bf16x8 gh, gl;
#pragma unroll
            for (int i = 0; i < 8; ++i) {
                float pre = bv[i >> 2][i & 3];
#pragma unroll
                for (int l = 0; l < 7; ++l) pre += xr[l] * wv[l][i >> 2][i & 3];
                float t = __expf(-2.0f * fabsf(pre));
                float r = fast_rcp(1.0f + t);
                float g = 4.0f * t * r * r;               // 1 - tanh^2(pre)
                unsigned short hu = f2bf(g);
                float lo = g - bf2f(hu);
                gh[i] = (short)hu;
                gl[i] = (short)f2bf(lo);
            }
            const int fi = (kk * 4 + arg) * 64 + alane;
            reinterpret_cast<bf16x8*>(Gh)[fi] = gh;
            reinterpret_cast<bf16x8*>(Gl)[fi] = gl;
        }
        __syncthreads();

        // ---- phase B: 3-term split-bf16 MFMA over this chunk ----
#pragma unroll
        for (int kk = 0; kk < 4; ++kk) {
            const int kkg = chunk * 4 + kk;
            bf16x8 bh[2], bl[2], ah[2], al[2];
#pragma unroll
            for (int nt = 0; nt < 2; ++nt) {
                const int f = (kkg * 8 + (wpg * 2 + nt)) * 64 + lane;
                bh[nt] = Vh[f];
                bl[nt] = Vl[f];
            }
#pragma unroll
            for (int rt = 0; rt < 2; ++rt) {
                const int fi = (kk * 4 + (wrg * 2 + rt)) * 64 + lane;
                ah[rt] = reinterpret_cast<const bf16x8*>(Gh)[fi];
                al[rt] = reinterpret_cast<const bf16x8*>(Gl)[fi];
            }
#pragma unroll
            for (int rt = 0; rt < 2; ++rt)
#pragma unroll
                for (int nt = 0; nt < 2; ++nt) {
                    acc[rt][nt] = __builtin_amdgcn_mfma_f32_32x32x16_bf16(ah[rt], bh[nt], acc[rt][nt], 0, 0, 0);
                    acc[rt][nt] = __builtin_amdgcn_mfma_f32_32x32x16_bf16(ah[rt], bl[nt], acc[rt][nt], 0, 0, 0);
                    acc[rt][nt] = __builtin_amdgcn_mfma_f32_32x32x16_bf16(al[rt], bh[nt], acc[rt][nt], 0, 0, 0);
                }
        }
        __syncthreads();
    }

    // ---- epilogue: per-sample 6*||J||^2 -> norm -> loss partials ----
    // D layout (verified): col = lane&31, row = (reg&3) + 8*(reg>>2) + 4*(lane>>5)
#pragma unroll
    for (int rt = 0; rt < 2; ++rt) {
#pragma unroll
        for (int reg = 0; reg < 16; ++reg) {
            float v = acc[rt][0][reg] * acc[rt][0][reg]
                    + acc[rt][1][reg] * acc[rt][1][reg];
#pragma unroll
            for (int m = 1; m <= 16; m <<= 1) v += __shfl_xor(v, m);
            if ((lane & 31) == 0) {
                const int row = wrg * 64 + rt * 32 + (reg & 3) + 8 * (reg >> 2) + 4 * (lane >> 5);
                red[wpg][row] = v;
            }
        }
    }
    __syncthreads();

    if (tid < 128) {
        float s = red[0][tid] + red[1][tid] + red[2][tid] + red[3][tid];
        float q = 6.0f * s;
        float n = sqrtf(q + 1e-10f);
        float d = n - KAPPA;
        red2[0][tid] = d * d;
        red2[1][tid] = n;
    }
    __syncthreads();

    if (tid < 64) {
        float a = red2[0][tid] + red2[0][tid + 64];
        float b = red2[1][tid] + red2[1][tid + 64];
#pragma unroll
        for (int m = 1; m <= 32; m <<= 1) {
            a += __shfl_xor(a, m);
            b += __shfl_xor(b, m);
        }
        if (tid == 0) {
            partials[blk]        = a;
            partials[NBLK + blk] = b;
        }
    }
}

// ---------------------------------------------------------------------------
// Kernel 3: finalize — deterministic sum of 256 per-block partials.
// ---------------------------------------------------------------------------
__global__ void finalize_k(const float* __restrict__ partials, float* __restrict__ out) {
    __shared__ float sl[256], sn[256];
    int tid = threadIdx.x;
    sl[tid] = partials[tid];
    sn[tid] = partials[NBLK + tid];
    __syncthreads();
    for (int st = 128; st > 0; st >>= 1) {
        if (tid < st) { sl[tid] += sl[tid + st]; sn[tid] += sn[tid + st]; }
        __syncthreads();
    }
    if (tid == 0) {
        out[0] = sl[0] / 32768.0f;
        out[1] = sn[0] / 32768.0f;
    }
}

// ---------------------------------------------------------------------------
extern "C" void kernel_launch(void* const* d_in, const int* in_sizes, int n_in,
                              void* d_out, int out_size, void* d_ws, size_t ws_size,
                              hipStream_t stream) {
    const float* x  = (const float*)d_in[0];
    const float* W1 = (const float*)d_in[1];
    const float* b1 = (const float*)d_in[2];
    const float* W2 = (const float*)d_in[3];
    // b2 (d_in[4]) unused: the Jacobian kills the bias.

    bf16x8* Vh       = (bf16x8*)d_ws;          // 16384 frags * 16 B = 256 KB
    bf16x8* Vl       = Vh + 16384;             // 256 KB
    float*  partials = (float*)(Vl + 16384);   // 512 floats

    build_v<<<64, 256, 0, stream>>>(W1, W2, Vh, Vl);
    torsion_main<<<NBLK, 512, 0, stream>>>(x, W1, b1, Vh, Vl, partials);
    finalize_k<<<1, 256, 0, stream>>>(partials, (float*)d_out);
}

// Round 3
// 38.818 us; speedup vs baseline: 3.7348x; 1.3620x over previous
//
#include <hip/hip_runtime.h>
#include <math.h>

typedef __attribute__((ext_vector_type(8)))  short bf16x8;
typedef __attribute__((ext_vector_type(16))) float f32x16;
typedef __attribute__((ext_vector_type(4)))  float f32x4v;

#define KAPPA (1.0f/61.0f)
#define NBLK 512           // 32768 rows / 64 rows-per-block

__device__ __forceinline__ unsigned short f2bf(float f) {
    unsigned int x = __float_as_uint(f);
    x += 0x7fffu + ((x >> 16) & 1u);               // RNE
    return (unsigned short)(x >> 16);
}
__device__ __forceinline__ float fast_rcp(float v) {
#if __has_builtin(__builtin_amdgcn_rcpf)
    return __builtin_amdgcn_rcpf(v);
#else
    return 1.0f / v;
#endif
}

// ---------------------------------------------------------------------------
// Kernel 1: V[h][p] = W1[l][h]*W2[h][c] (p = l*35+c, padded to 256), single
// bf16, 32x32x16-MFMA B-fragment layout:
//   frag f = (kkg*8 + ntg)*64 + lane holds B[k = kkg*16+(lane>>5)*8+i][p = ntg*32+(lane&31)]
// ---------------------------------------------------------------------------
__global__ void build_v(const float* __restrict__ W1, const float* __restrict__ W2,
                        bf16x8* __restrict__ V) {
    int f = blockIdx.x * blockDim.x + threadIdx.x;   // 0..16383
    if (f >= 32 * 8 * 64) return;
    int lane = f & 63;
    int ntg  = (f >> 6) & 7;
    int kkg  = f >> 9;
    int p     = ntg * 32 + (lane & 31);
    int hbase = kkg * 16 + (lane >> 5) * 8;
    bool valid = (p < 245);
    int l7 = valid ? p / 35 : 0;
    int c  = valid ? p - l7 * 35 : 0;
    bf16x8 vh;
#pragma unroll
    for (int i = 0; i < 8; ++i) {
        int h = hbase + i;
        float v = valid ? (W1[l7 * 512 + h] * W2[h * 35 + c]) : 0.0f;
        vh[i] = (short)f2bf(v);
    }
    V[f] = vh;
}

// ---------------------------------------------------------------------------
// Kernel 2: main. 256 threads = 4 waves; block tile 64 rows x 256 p.
// Wave = one p-group (64 p); all waves share G (A-frags) via LDS.
// Triple-buffered G -> ONE barrier per 64-k chunk. 512 blocks -> 2 blocks/CU
// so VALU phase (tanh) of one block overlaps MFMA phase of the other.
// ---------------------------------------------------------------------------
__global__ __launch_bounds__(256, 2)
void torsion_main(const float* __restrict__ x, const float* __restrict__ W1,
                  const float* __restrict__ b1, const bf16x8* __restrict__ V,
                  float* __restrict__ partials) {
    __shared__ float W1s[7 * 512];
    __shared__ float b1s[512];
    __shared__ __align__(16) short G[3][4][2][64][8];  // [buf][kk][rt][lane][8]
    __shared__ float red[4][64];

    const int tid  = threadIdx.x;
    const int lane = tid & 63;
    const int w    = tid >> 6;        // wave = p-group 0..3; also kk-slot in phase A
    const int blk  = blockIdx.x;

    for (int i = tid; i < 7 * 512; i += 256) W1s[i] = W1[i];
    if (tid < 512 && tid >= 256) {}   // (no-op; keep b1 load simple below)
    for (int i = tid; i < 512; i += 256) b1s[i] = b1[i];

    // x rows for this thread's two A-frag rows: (lane&31) and 32+(lane&31)
    float xr[2][7];
    {
        const float* xp0 = x + ((size_t)blk * 64 + (lane & 31)) * 7;
#pragma unroll
        for (int l = 0; l < 7; ++l) {
            xr[0][l] = xp0[l];
            xr[1][l] = xp0[32 * 7 + l];
        }
    }

    f32x16 acc[2][2];
#pragma unroll
    for (int rt = 0; rt < 2; ++rt)
#pragma unroll
        for (int nt = 0; nt < 2; ++nt)
#pragma unroll
            for (int e = 0; e < 16; ++e) acc[rt][nt][e] = 0.0f;

    __syncthreads();   // W1s/b1s ready

    // Phase A: g = 1 - tanh^2(x@W1+b1) = 4t/(1+t)^2, t = e^(-2|pre|),
    // packed bf16 directly in A-frag layout (frag kk=w, rt=j).
#define PHASEA(CH, BUF) do {                                                   \
        const int kbase = (CH) * 64 + w * 16 + ((lane >> 5) << 3);             \
        f32x4v wv[7][2];                                                       \
        _Pragma("unroll")                                                      \
        for (int l = 0; l < 7; ++l) {                                          \
            wv[l][0] = *reinterpret_cast<const f32x4v*>(&W1s[l * 512 + kbase]);    \
            wv[l][1] = *reinterpret_cast<const f32x4v*>(&W1s[l * 512 + kbase + 4]);\
        }                                                                      \
        f32x4v bv0 = *reinterpret_cast<const f32x4v*>(&b1s[kbase]);            \
        f32x4v bv1 = *reinterpret_cast<const f32x4v*>(&b1s[kbase + 4]);        \
        _Pragma("unroll")                                                      \
        for (int j = 0; j < 2; ++j) {                                          \
            bf16x8 gpk;                                                        \
            _Pragma("unroll")                                                  \
            for (int i = 0; i < 8; ++i) {                                      \
                float pre = (i < 4) ? bv0[i & 3] : bv1[i & 3];                 \
                _Pragma("unroll")                                              \
                for (int l = 0; l < 7; ++l)                                    \
                    pre += xr[j][l] * ((i < 4) ? wv[l][0][i & 3] : wv[l][1][i & 3]); \
                float t = __expf(-2.0f * fabsf(pre));                          \
                float r = fast_rcp(1.0f + t);                                  \
                float tr = 2.0f * r;                                           \
                float g = t * tr * tr;                                         \
                gpk[i] = (short)f2bf(g);                                       \
            }                                                                  \
            *reinterpret_cast<bf16x8*>(&G[BUF][w][j][lane][0]) = gpk;          \
        }                                                                      \
    } while (0)

    PHASEA(0, 0);
    __syncthreads();

#pragma unroll
    for (int c = 0; c < 8; ++c) {
        if (c < 7) PHASEA(c + 1, (c + 1) % 3);
        __syncthreads();
        const int ib = c % 3;
#pragma unroll
        for (int kk = 0; kk < 4; ++kk) {
            bf16x8 a0 = *reinterpret_cast<const bf16x8*>(&G[ib][kk][0][lane][0]);
            bf16x8 a1 = *reinterpret_cast<const bf16x8*>(&G[ib][kk][1][lane][0]);
            const int fb = ((c * 4 + kk) * 8 + w * 2) * 64 + lane;
            bf16x8 b0 = V[fb];
            bf16x8 b1f = V[fb + 64];
            acc[0][0] = __builtin_amdgcn_mfma_f32_32x32x16_bf16(a0, b0,  acc[0][0], 0, 0, 0);
            acc[0][1] = __builtin_amdgcn_mfma_f32_32x32x16_bf16(a0, b1f, acc[0][1], 0, 0, 0);
            acc[1][0] = __builtin_amdgcn_mfma_f32_32x32x16_bf16(a1, b0,  acc[1][0], 0, 0, 0);
            acc[1][1] = __builtin_amdgcn_mfma_f32_32x32x16_bf16(a1, b1f, acc[1][1], 0, 0, 0);
        }
    }

    // ---- epilogue: per-sample 6*||J||^2 -> norm -> loss partials ----
    // D layout (verified r2): col = lane&31, row = (reg&3) + 8*(reg>>2) + 4*(lane>>5)
#pragma unroll
    for (int rt = 0; rt < 2; ++rt) {
#pragma unroll
        for (int reg = 0; reg < 16; ++reg) {
            float v = acc[rt][0][reg] * acc[rt][0][reg]
                    + acc[rt][1][reg] * acc[rt][1][reg];
#pragma unroll
            for (int m = 1; m <= 16; m <<= 1) v += __shfl_xor(v, m);
            if ((lane & 31) == 0) {
                red[w][rt * 32 + (reg & 3) + 8 * (reg >> 2) + 4 * (lane >> 5)] = v;
            }
        }
    }
    __syncthreads();

    if (tid < 64) {
        float s = red[0][tid] + red[1][tid] + red[2][tid] + red[3][tid];
        float q = 6.0f * s;
        float n = sqrtf(q + 1e-10f);
        float d = n - KAPPA;
        float a = d * d, bsum = n;
#pragma unroll
        for (int m = 1; m <= 32; m <<= 1) {
            a    += __shfl_xor(a, m);
            bsum += __shfl_xor(bsum, m);
        }
        if (tid == 0) {
            partials[blk]        = a;
            partials[NBLK + blk] = bsum;
        }
    }
}

// ---------------------------------------------------------------------------
// Kernel 3: finalize — deterministic sum of 512 per-block partials.
// ---------------------------------------------------------------------------
__global__ void finalize_k(const float* __restrict__ partials, float* __restrict__ out) {
    __shared__ float sl[256], sn[256];
    int tid = threadIdx.x;
    sl[tid] = partials[tid] + partials[tid + 256];
    sn[tid] = partials[NBLK + tid] + partials[NBLK + tid + 256];
    __syncthreads();
    for (int st = 128; st > 0; st >>= 1) {
        if (tid < st) { sl[tid] += sl[tid + st]; sn[tid] += sn[tid + st]; }
        __syncthreads();
    }
    if (tid == 0) {
        out[0] = sl[0] / 32768.0f;
        out[1] = sn[0] / 32768.0f;
    }
}

// ---------------------------------------------------------------------------
extern "C" void kernel_launch(void* const* d_in, const int* in_sizes, int n_in,
                              void* d_out, int out_size, void* d_ws, size_t ws_size,
                              hipStream_t stream) {
    const float* x  = (const float*)d_in[0];
    const float* W1 = (const float*)d_in[1];
    const float* b1 = (const float*)d_in[2];
    const float* W2 = (const float*)d_in[3];
    // b2 (d_in[4]) unused: the Jacobian kills the bias.

    bf16x8* V        = (bf16x8*)d_ws;          // 16384 frags * 16 B = 256 KB
    float*  partials = (float*)(V + 16384);    // 1024 floats

    build_v<<<64, 256, 0, stream>>>(W1, W2, V);
    torsion_main<<<NBLK, 256, 0, stream>>>(x, W1, b1, V, partials);
    finalize_k<<<1, 256, 0, stream>>>(partials, (float*)d_out);
}

// Round 4
// 27.688 us; speedup vs baseline: 5.2361x; 1.4020x over previous
//
#include <hip/hip_runtime.h>
#include <hip/hip_bf16.h>
#include <math.h>

typedef __attribute__((ext_vector_type(8)))  short bf16x8;
typedef __attribute__((ext_vector_type(16))) float f32x16;
typedef unsigned int u32;

#define KAPPA (1.0f/61.0f)
#define NBLK 512           // 32768 rows / 64 rows-per-block

__device__ __forceinline__ unsigned short f2bf(float f) {
    u32 x = __float_as_uint(f);
    x += 0x7fffu + ((x >> 16) & 1u);               // RNE
    return (unsigned short)(x >> 16);
}
__device__ __forceinline__ float fast_rcp(float v) {
#if __has_builtin(__builtin_amdgcn_rcpf)
    return __builtin_amdgcn_rcpf(v);
#else
    return 1.0f / v;
#endif
}
__device__ __forceinline__ u32 pack_bf16(float lo, float hi) {
    __hip_bfloat162 p = __float22bfloat162_rn(make_float2(lo, hi));  // v_cvt_pk path
    return *reinterpret_cast<u32*>(&p);
}

// ---------------------------------------------------------------------------
// Kernel 1: precompute MFMA operand fragments (all sample-independent).
//  V  frags [16384]: f=(kkg*8+ptile)*64+lane -> A-frag of V^T:
//       row p = ptile*32+(lane&31), k h = kkg*16+(lane>>5)*8+i
//       V[h][p] = W1[l][h]*W2[h][c], p=l*35+c (pad 245->256)
//  Wt frags [1024]:  f=htile*64+lane -> A-frag of [W1^T | b1]:
//       row h = htile*32+(lane&31); lo half k=0..6 -> W1[k][h], k=7 -> b1[h]; hi 0
// ---------------------------------------------------------------------------
__global__ void build_v(const float* __restrict__ W1, const float* __restrict__ W2,
                        const float* __restrict__ b1,
                        bf16x8* __restrict__ V, bf16x8* __restrict__ Wt) {
    int t = blockIdx.x * blockDim.x + threadIdx.x;
    if (t < 16384) {
        int lane = t & 63, ptile = (t >> 6) & 7, kkg = t >> 9;
        int p  = ptile * 32 + (lane & 31);
        int hb = kkg * 16 + (lane >> 5) * 8;
        bool valid = (p < 245);
        int l7 = valid ? p / 35 : 0;
        int c  = valid ? p - l7 * 35 : 0;
        bf16x8 v;
#pragma unroll
        for (int i = 0; i < 8; ++i) {
            int h = hb + i;
            v[i] = valid ? (short)f2bf(W1[l7 * 512 + h] * W2[h * 35 + c]) : (short)0;
        }
        V[t] = v;
    } else if (t < 16384 + 1024) {
        int f = t - 16384;
        int lane = f & 63, htile = f >> 6;
        int h = htile * 32 + (lane & 31);
        bf16x8 v;
#pragma unroll
        for (int i = 0; i < 8; ++i) v[i] = 0;
        if (lane < 32) {
#pragma unroll
            for (int l = 0; l < 7; ++l) v[l] = (short)f2bf(W1[l * 512 + h]);
            v[7] = (short)f2bf(b1[h]);
        }
        Wt[f] = v;
    }
}

// ---------------------------------------------------------------------------
// Kernel 2: main. 256 threads = 4 waves; block tile 64 samples x 256 p.
// Wave w: pre-tile (htile = w>>1, rowtile = w&1); main p-tiles {2w, 2w+1}.
// Per 64-h chunk: pre^T = mfma(W1^T, x) -> g elementwise -> pack -> 4x
// ds_write_b64 lands directly in G^T B-frag layout (addressing = transpose).
// Double-buffered, ONE barrier per chunk.
// ---------------------------------------------------------------------------
__global__ __launch_bounds__(256, 3)
void torsion_main(const float* __restrict__ x,
                  const bf16x8* __restrict__ V, const bf16x8* __restrict__ Wt,
                  float* __restrict__ partials) {
    __shared__ __align__(16) u32 Gb[2][8][64 * 4];   // [buf][ks*2+rt][lane dwords] = 16KB
    __shared__ float red[4][2][32];

    const int tid  = threadIdx.x;
    const int lane = tid & 63;
    const int w    = tid >> 6;
    const int blk  = blockIdx.x;
    const int rt   = w & 1;      // row-tile this wave's pre covers
    const int ht   = w >> 1;     // h-subtile (0..1) within chunk

    // x B-frag (once): col = sample, lo half k=0..6 -> x, k=7 -> 1.0; hi half 0
    bf16x8 xf;
#pragma unroll
    for (int i = 0; i < 8; ++i) xf[i] = 0;
    if (lane < 32) {
        const float* xp = x + ((size_t)blk * 64 + rt * 32 + lane) * 7;
#pragma unroll
        for (int l = 0; l < 7; ++l) xf[l] = (short)f2bf(xp[l]);
        xf[7] = (short)f2bf(1.0f);
    }

    f32x16 acc[2][2];
#pragma unroll
    for (int pt = 0; pt < 2; ++pt)
#pragma unroll
        for (int r2 = 0; r2 < 2; ++r2)
#pragma unroll
            for (int e = 0; e < 16; ++e) acc[pt][r2][e] = 0.0f;

    // pre^T tile for chunk c -> 8 packed dwords of g (bf16 pairs)
    auto pre_pack = [&](int c, u32 d[8]) {
        bf16x8 wf = Wt[(c * 2 + ht) * 64 + lane];
        f32x16 p;
#pragma unroll
        for (int e = 0; e < 16; ++e) p[e] = 0.0f;
        p = __builtin_amdgcn_mfma_f32_32x32x16_bf16(wf, xf, p, 0, 0, 0);
#pragma unroll
        for (int j = 0; j < 8; ++j) {
            float g0, g1;
            {
                float t0 = __expf(-2.0f * fabsf(p[2 * j]));
                float r0 = fast_rcp(1.0f + t0);
                g0 = 4.0f * t0 * r0 * r0;
                float t1 = __expf(-2.0f * fabsf(p[2 * j + 1]));
                float r1 = fast_rcp(1.0f + t1);
                g1 = 4.0f * t1 * r1 * r1;
            }
            d[j] = pack_bf16(g0, g1);
        }
    };
    // store: lane's dwords -> G^T B-frags via addressing (free transpose)
    auto store_g = [&](int buf, const u32 d[8]) {
        const int f0  = (2 * ht) * 2 + rt;       // frag idx for kstep 2*ht
        const int f1  = f0 + 2;                  // kstep 2*ht+1
        const int col = lane & 31;
        const int hw2 = (lane >> 5) << 1;        // 0 or 2 dwords
        *reinterpret_cast<uint2*>(&Gb[buf][f0][(col      ) * 4 + hw2]) = make_uint2(d[0], d[1]);
        *reinterpret_cast<uint2*>(&Gb[buf][f0][(col + 32 ) * 4 + hw2]) = make_uint2(d[2], d[3]);
        *reinterpret_cast<uint2*>(&Gb[buf][f1][(col      ) * 4 + hw2]) = make_uint2(d[4], d[5]);
        *reinterpret_cast<uint2*>(&Gb[buf][f1][(col + 32 ) * 4 + hw2]) = make_uint2(d[6], d[7]);
    };

    {
        u32 d[8];
        pre_pack(0, d);
        store_g(0, d);
    }
    __syncthreads();

    for (int c = 0; c < 8; ++c) {
        const int buf = c & 1;
        u32 dn[8];
        if (c < 7) pre_pack(c + 1, dn);
#pragma unroll
        for (int ks = 0; ks < 4; ++ks) {
            bf16x8 g0 = *reinterpret_cast<const bf16x8*>(&Gb[buf][ks * 2 + 0][lane * 4]);
            bf16x8 g1 = *reinterpret_cast<const bf16x8*>(&Gb[buf][ks * 2 + 1][lane * 4]);
            const int fb = ((c * 4 + ks) * 8 + 2 * w) * 64 + lane;
            bf16x8 va = V[fb];
            bf16x8 vb = V[fb + 64];
            acc[0][0] = __builtin_amdgcn_mfma_f32_32x32x16_bf16(va, g0, acc[0][0], 0, 0, 0);
            acc[0][1] = __builtin_amdgcn_mfma_f32_32x32x16_bf16(va, g1, acc[0][1], 0, 0, 0);
            acc[1][0] = __builtin_amdgcn_mfma_f32_32x32x16_bf16(vb, g0, acc[1][0], 0, 0, 0);
            acc[1][1] = __builtin_amdgcn_mfma_f32_32x32x16_bf16(vb, g1, acc[1][1], 0, 0, 0);
        }
        if (c < 7) store_g(buf ^ 1, dn);
        __syncthreads();
    }

    // ---- epilogue: D2[p][sample]: col = sample, regs = p-slice.
    // lane and lane^32 hold complementary p-halves of the SAME sample.
#pragma unroll
    for (int r2 = 0; r2 < 2; ++r2) {
        float s = 0.0f;
#pragma unroll
        for (int pt = 0; pt < 2; ++pt)
#pragma unroll
            for (int e = 0; e < 16; ++e) s += acc[pt][r2][e] * acc[pt][r2][e];
        s += __shfl_xor(s, 32);
        if (lane < 32) red[w][r2][lane] = s;
    }
    __syncthreads();

    if (tid < 64) {
        const int li = tid & 31, rr = tid >> 5;
        float q = 6.0f * (red[0][rr][li] + red[1][rr][li] + red[2][rr][li] + red[3][rr][li]);
        float n = sqrtf(q + 1e-10f);
        float d = n - KAPPA;
        float a = d * d, b = n;
#pragma unroll
        for (int m = 1; m <= 32; m <<= 1) {
            a += __shfl_xor(a, m);
            b += __shfl_xor(b, m);
        }
        if (tid == 0) {
            partials[blk]        = a;
            partials[NBLK + blk] = b;
        }
    }
}

// ---------------------------------------------------------------------------
// Kernel 3: finalize — deterministic sum of 512 per-block partials.
// ---------------------------------------------------------------------------
__global__ void finalize_k(const float* __restrict__ partials, float* __restrict__ out) {
    __shared__ float sl[256], sn[256];
    int tid = threadIdx.x;
    sl[tid] = partials[tid] + partials[tid + 256];
    sn[tid] = partials[NBLK + tid] + partials[NBLK + tid + 256];
    __syncthreads();
    for (int st = 128; st > 0; st >>= 1) {
        if (tid < st) { sl[tid] += sl[tid + st]; sn[tid] += sn[tid + st]; }
        __syncthreads();
    }
    if (tid == 0) {
        out[0] = sl[0] / 32768.0f;
        out[1] = sn[0] / 32768.0f;
    }
}

// ---------------------------------------------------------------------------
extern "C" void kernel_launch(void* const* d_in, const int* in_sizes, int n_in,
                              void* d_out, int out_size, void* d_ws, size_t ws_size,
                              hipStream_t stream) {
    const float* x  = (const float*)d_in[0];
    const float* W1 = (const float*)d_in[1];
    const float* b1 = (const float*)d_in[2];
    const float* W2 = (const float*)d_in[3];
    // b2 (d_in[4]) unused: the Jacobian kills the bias.

    bf16x8* V        = (bf16x8*)d_ws;          // 16384 frags * 16 B = 256 KB
    bf16x8* Wt       = V + 16384;              // 1024 frags * 16 B = 16 KB
    float*  partials = (float*)(Wt + 1024);    // 1024 floats

    build_v<<<68, 256, 0, stream>>>(W1, W2, b1, V, Wt);
    torsion_main<<<NBLK, 256, 0, stream>>>(x, V, Wt, partials);
    finalize_k<<<1, 256, 0, stream>>>(partials, (float*)d_out);
}